// Round 16
// baseline (108.807 us; speedup 1.0000x reference)
//
#include <hip/hip_runtime.h>

typedef unsigned short u16;
typedef unsigned int u32;
typedef __attribute__((ext_vector_type(8))) __bf16 bf16x8;
typedef __attribute__((ext_vector_type(4))) float f32x4;
typedef __attribute__((ext_vector_type(4))) u16 u16x4;

#define MFMA16(a, b, c) __builtin_amdgcn_mfma_f32_16x16x32_bf16((a), (b), (c), 0, 0, 0)

static __device__ __forceinline__ u16 f2b(float f) {
  union { float f; u32 u; } v; v.f = f;
  u32 u = v.u;
  return (u16)((u + 0x7FFFu + ((u >> 16) & 1u)) >> 16);
}

// packed f32x2 -> bf16x2 (RNE), low half = a
static __device__ __forceinline__ u32 pack2(float a, float b) {
  u32 r;
  asm("v_cvt_pk_bf16_f32 %0, %1, %2" : "=v"(r) : "v"(a), "v"(b));
  return r;
}

static __device__ __forceinline__ float exp2fast(float x) {
#if defined(__has_builtin) && __has_builtin(__builtin_amdgcn_exp2f)
  return __builtin_amdgcn_exp2f(x);
#else
  return __expf(x * 0.6931471805599453f);
#endif
}

static __device__ __forceinline__ void gload16(const u16* gp, u16* lp) {
  __builtin_amdgcn_global_load_lds((__attribute__((address_space(1))) void*)(u16*)gp,
                                   (__attribute__((address_space(3))) void*)lp, 16, 0, 0);
}

// ---------------- merged prep kernel ----------------
__global__ __launch_bounds__(256) void k_prep(const float* __restrict__ Wqkv, const float* __restrict__ Wout,
                                              const float* __restrict__ W1p, const float* __restrict__ W2p,
                                              const float* __restrict__ x,
                                              u16* __restrict__ WB, u16* __restrict__ WoT,
                                              u16* __restrict__ xb) {
  const int b = blockIdx.x;
  const int t = threadIdx.x;
  if (b < 1024) {
    __shared__ float tile[64][65];
    const float* src; u16* dst; int N, n0, k0;
    if (b < 768) { src = Wqkv; dst = WB;  N = 3072; n0 = (b % 48) * 64; k0 = (b / 48) * 64; }
    else { const int bb = b - 768; src = Wout; dst = WoT; N = 1024; n0 = (bb & 15) * 64; k0 = (bb >> 4) * 64; }
    const int rr = t >> 4, cc = (t & 15) << 2;
#pragma unroll
    for (int i = 0; i < 4; ++i) {
      const float4 v = *(const float4*)(src + (size_t)(k0 + rr + i * 16) * N + n0 + cc);
      tile[rr + i * 16][cc + 0] = v.x; tile[rr + i * 16][cc + 1] = v.y;
      tile[rr + i * 16][cc + 2] = v.z; tile[rr + i * 16][cc + 3] = v.w;
    }
    __syncthreads();
    const int nr = t >> 3, kc = (t & 7) << 3;
#pragma unroll
    for (int i = 0; i < 2; ++i) {
      u16 o[8];
#pragma unroll
      for (int j = 0; j < 8; ++j) o[j] = f2b(tile[kc + j][nr + i * 32]);
      *(uint4*)(dst + (size_t)(n0 + nr + i * 32) * 1024 + k0 + kc) = *(const uint4*)o;
    }
  } else if (b < 1536) {
    const int idx = (b - 1024) * 256 + t;  // 131072
    const int j = idx >> 10, k = idx & 1023;
    const float v = (j < 64) ? W1p[(size_t)k * 64 + j] : W2p[(size_t)k * 64 + (j - 64)];
    WB[(size_t)3072 * 1024 + idx] = f2b(v);
  } else {
    const size_t idx = ((size_t)(b - 1536) * 256 + t) << 2;
    const float4 v = *(const float4*)(x + idx);
    u16x4 o; o.x = f2b(v.x); o.y = f2b(v.y); o.z = f2b(v.z); o.w = f2b(v.w);
    *(u16x4*)(xb + idx) = o;
  }
}

// ---------------- 128x64 bf16 MFMA GEMM core (BK=64, global_load_lds, XOR swizzle) ----------------
static __device__ __forceinline__ void gemm_core_128x64(const u16* __restrict__ A, const u16* __restrict__ B,
                                                        int brow, int bcol, int K,
                                                        u16* ldsA, u16* ldsB, f32x4 acc[4][2]) {
  const int tid = threadIdx.x;
  const int wave = tid >> 6, lane = tid & 63;
  const int wr = wave >> 1, wc = wave & 1;
  const int g = lane >> 4, l15 = lane & 15;

  for (int k0 = 0; k0 < K; k0 += 64) {
#pragma unroll
    for (int li = 0; li < 4; ++li) {
      const int f = li * 256 + wave * 64 + lane;
      const int row = f >> 3;
      const int slot = f & 7;
      const int gcol = ((slot ^ (row & 7)) << 3);
      gload16(A + (size_t)(brow + row) * K + k0 + gcol, ldsA + (size_t)(li * 256 + wave * 64) * 8);
    }
#pragma unroll
    for (int li = 0; li < 2; ++li) {
      const int f = li * 256 + wave * 64 + lane;
      const int row = f >> 3;
      const int slot = f & 7;
      const int gcol = ((slot ^ (row & 7)) << 3);
      gload16(B + (size_t)(bcol + row) * K + k0 + gcol, ldsB + (size_t)(li * 256 + wave * 64) * 8);
    }
    __syncthreads();
    bf16x8 af[4][2], bfr[2][2];
#pragma unroll
    for (int kk = 0; kk < 2; ++kk) {
#pragma unroll
      for (int m = 0; m < 4; ++m) {
        const int rowA = wr * 64 + m * 16 + l15;
        const int chA = (kk * 4 + g) ^ (rowA & 7);
        af[m][kk] = *(const bf16x8*)(ldsA + (size_t)rowA * 64 + chA * 8);
      }
#pragma unroll
      for (int n = 0; n < 2; ++n) {
        const int rowB = wc * 32 + n * 16 + l15;
        const int chB = (kk * 4 + g) ^ (rowB & 7);
        bfr[n][kk] = *(const bf16x8*)(ldsB + (size_t)rowB * 64 + chB * 8);
      }
    }
#pragma unroll
    for (int m = 0; m < 4; ++m)
#pragma unroll
      for (int n = 0; n < 2; ++n)
#pragma unroll
        for (int kk = 0; kk < 2; ++kk)
          acc[m][n] = MFMA16(af[m][kk], bfr[n][kk], acc[m][n]);
    __syncthreads();
  }
}

// ---------------- GEMM1: x @ [Wqkv|W1p|W2p]  (M=2048, N=3200, K=1024), 128x64 tile ----------------
// ONE change vs R15: PERSISTENT blocks + atomic work-steal. 768 blocks (3/CU residency kept),
// each does tile blockIdx.x then pulls tiles 768..799 from *counter (device-scope atomic,
// zeroed via hipMemsetAsync). Inner loop/epilogue byte-identical. Fixes the 4-vs-3.125
// block-per-CU makespan tail.
__global__ __launch_bounds__(256) void k_gemm_qkvp(const u16* __restrict__ xb, const u16* __restrict__ WB,
                                                   const float* __restrict__ bqkv,
                                                   u16* __restrict__ Qext, u16* __restrict__ Kf,
                                                   u16* __restrict__ Vt, float* __restrict__ P12,
                                                   u32* __restrict__ counter) {
  __shared__ __align__(16) u16 ldsA[128 * 64];
  __shared__ __align__(16) u16 ldsB[64 * 64];
  const int tid = threadIdx.x;
  const int wave = tid >> 6, lane = tid & 63;
  const int wr = wave >> 1, wc = wave & 1;
  const int g = lane >> 4, l15 = lane & 15;
  __shared__ int next_tile;

  int tile = blockIdx.x;                           // 768 blocks; tiles 0..799
  while (tile < 800) {
    const int bn = tile % 50, bm = tile / 50;
    f32x4 acc[4][2];
#pragma unroll
    for (int m = 0; m < 4; ++m)
#pragma unroll
      for (int n = 0; n < 2; ++n) acc[m][n] = (f32x4){0.f, 0.f, 0.f, 0.f};
    gemm_core_128x64(xb, WB, bm * 128, bn * 64, 1024, ldsA, ldsB, acc);

    const int tbase = bm * 128 + wr * 64 + g * 4;
    const int cbase = bn * 64 + wc * 32 + l15;
#pragma unroll
    for (int m = 0; m < 4; ++m) {
#pragma unroll
      for (int n = 0; n < 2; ++n) {
        const int c = cbase + n * 16;
#pragma unroll
        for (int r = 0; r < 4; ++r) {
          const int t = tbase + m * 16 + r;
          float v = acc[m][n][r];
          if (c < 3072) {
            v += bqkv[c];
            const int sub = c >> 10;
            const int rem = c & 1023;
            const int hh = rem >> 6, d = rem & 63;
            if (sub == 0) {
              Qext[((size_t)hh * 2048 + t) * 96 + d] = f2b(v * 0.18033688f);
            } else if (sub == 1) {
              const int jt2 = t >> 5, hf = (t >> 4) & 1, l15t = t & 15;
              const int ks2 = d >> 5, gg = (d >> 3) & 3, e = d & 7;
              Kf[(size_t)hh * 196608 + (size_t)jt2 * 3072 + (hf * 3 + ks2) * 512 + (gg * 16 + l15t) * 8 + e] = f2b(v);
            } else {
              Vt[(size_t)hh * 131072 + (size_t)(t >> 5) * 2048 + d * 32 + (t & 31)] = f2b(v);
            }
          } else {
            P12[(size_t)t * 128 + (c - 3072)] = v;
          }
        }
      }
    }
    // pull next tile (device-scope atomic); one lane per block, broadcast via LDS
    if (tid == 0) next_tile = 768 + (int)atomicAdd(counter, 1u);
    __syncthreads();
    tile = next_tile;
    __syncthreads();
  }
}

// ---------------- Plucker lines -> Qext cols 64..95 + Kf fragment block ks=2 ----------------
__global__ __launch_bounds__(256) void k_lines(const float* __restrict__ P12, const float* __restrict__ pscale,
                                               u16* __restrict__ Qext, u16* __restrict__ Kf) {
  const int idx = blockIdx.x * 256 + threadIdx.x;  // 32768 = 2048*16
  const int t = idx >> 4, h = idx & 15;
  const float* p = P12 + (size_t)t * 128;
  const float a0 = p[h * 4 + 0], a1 = p[h * 4 + 1], a2 = p[h * 4 + 2], a3 = p[h * 4 + 3];
  const float b0 = p[64 + h * 4 + 0], b1 = p[64 + h * 4 + 1], b2 = p[64 + h * 4 + 2], b3 = p[64 + h * 4 + 3];
  float L0 = a0 * b1 - a1 * b0;
  float L1 = a0 * b2 - a2 * b0;
  float L2 = a0 * b3 - a3 * b0;
  float L3 = a1 * b2 - a2 * b1;
  float L4 = a1 * b3 - a3 * b1;
  float L5 = a2 * b3 - a3 * b2;
  const float nrm = sqrtf(L0 * L0 + L1 * L1 + L2 * L2 + L3 * L3 + L4 * L4 + L5 * L5);
  const float inv = 1.0f / fmaxf(nrm, 1e-12f);
  L0 *= inv; L1 *= inv; L2 *= inv; L3 *= inv; L4 *= inv; L5 *= inv;
  const float s = pscale[h] * 1.44269504f;  // fold log2(e) into q-side bias
  u16* q = Qext + ((size_t)h * 2048 + t) * 96 + 64;
  q[0] = f2b(L0 * s); q[1] = f2b(L1 * s); q[2] = f2b(L2 * s);
  q[3] = f2b(L3 * s); q[4] = f2b(L4 * s); q[5] = f2b(L5 * s);
#pragma unroll
  for (int c = 6; c < 32; ++c) q[c] = 0;
  // Jlines = J6 @ L : [L5, -L4, L3, L2, -L1, L0] -> fragment-order block z = half*3+2
  const float kv0 = L5, kv1 = -L4, kv2 = L3, kv3 = L2, kv4 = -L1, kv5 = L0;
  const int jt = t >> 5, hf = (t >> 4) & 1, l15t = t & 15;
  u16* kf = Kf + (size_t)h * 196608 + (size_t)jt * 3072 + (hf * 3 + 2) * 512;
#pragma unroll
  for (int j = 0; j < 32; ++j) {
    const int gg = (j >> 3) & 3, e = j & 7;
    float val;
    if (j == 0) val = kv0; else if (j == 1) val = kv1; else if (j == 2) val = kv2;
    else if (j == 3) val = kv3; else if (j == 4) val = kv4; else if (j == 5) val = kv5;
    else val = 0.f;
    kf[(gg * 16 + l15t) * 8 + e] = (j < 6) ? f2b(val) : (u16)0;
  }
}

// ---------------- fused causal attention: paired dual-stream + pipelined, fragment-order K ----------------
__global__ __launch_bounds__(64) void k_attn(const u16* __restrict__ Qext, const u16* __restrict__ Kf,
                                             const u16* __restrict__ Vt, u16* __restrict__ AO) {
  const int bid = blockIdx.x;                     // 1024 blocks = 16 heads x 64 pairs
  const int h = bid & 15;
  const int p = bid >> 4;                         // 0..63
  const int lane = threadIdx.x;
  const int g = lane >> 4, l15 = lane & 15;
  const int q0A = p << 4;
  const int q0B = (127 - p) << 4;
  const int qgA = q0A + l15;
  const int qgB = q0B + l15;
  const int sA = (p >> 1) + 1;                    // steps for tile A
  const int sB = ((127 - p) >> 1) + 1;            // steps for tile B (> sA)
  const u16* Qh = Qext + (size_t)h * 2048 * 96;
  const u16* Kfrag = Kf + (size_t)h * 196608;     // + jt*3072 + z*512 + lane*8
  const u16* Vh = Vt + (size_t)h * 131072;

  bf16x8 aqA[3], aqB[3];
#pragma unroll
  for (int ks = 0; ks < 3; ++ks) {
    aqA[ks] = *(const bf16x8*)(Qh + (size_t)qgA * 96 + ks * 32 + g * 8);
    aqB[ks] = *(const bf16x8*)(Qh + (size_t)qgB * 96 + ks * 32 + g * 8);
  }

  f32x4 accA[4], accB[4];
#pragma unroll
  for (int n = 0; n < 4; ++n) {
    accA[n] = (f32x4){0.f, 0.f, 0.f, 0.f};
    accB[n] = (f32x4){0.f, 0.f, 0.f, 0.f};
  }
  float lA = 0.f, lB = 0.f;

  const u16* Vlane = Vh + (size_t)l15 * 32 + g * 8;   // + jt*2048 + n*512
  const int laneoff = lane * 8;

  bf16x8 kX0[3], kX1[3], kY0[3], kY1[3];
  bf16x8 avX[4], avY[4];
  f32x4 SA0c, SA1c, SB0c, SB1c, SA0n, SA1n, SB0n, SB1n;

  // ---- prologue: K(0)->kX, S(0), K(1)->kY, V(0)->avX
  {
    const u16* kp0 = Kfrag + laneoff;
#pragma unroll
    for (int ks = 0; ks < 3; ++ks) {
      kX0[ks] = *(const bf16x8*)(kp0 + ks * 512);
      kX1[ks] = *(const bf16x8*)(kp0 + (3 + ks) * 512);
    }
    SB0c = (f32x4){0.f, 0.f, 0.f, 0.f}; SB1c = SB0c; SA0c = SB0c; SA1c = SB0c;
#pragma unroll
    for (int ks = 0; ks < 3; ++ks) {
      SB0c = MFMA16(kX0[ks], aqB[ks], SB0c);
      SB1c = MFMA16(kX1[ks], aqB[ks], SB1c);
      SA0c = MFMA16(kX0[ks], aqA[ks], SA0c);
      SA1c = MFMA16(kX1[ks], aqA[ks], SA1c);
    }
    const u16* kp = Kfrag + (size_t)((1 < sB) ? 1 : 0) * 3072 + laneoff;
#pragma unroll
    for (int ks = 0; ks < 3; ++ks) {
      kY0[ks] = *(const bf16x8*)(kp + ks * 512);
      kY1[ks] = *(const bf16x8*)(kp + (3 + ks) * 512);
    }
#pragma unroll
    for (int n = 0; n < 4; ++n) avX[n] = *(const bf16x8*)(Vlane + n * 512);
  }

#define GLUE(S0, S1, Q0S, QGS, LS, PBS)                                           \
  {                                                                               \
    if (jb + 31 > Q0S) {                                                          \
      _Pragma("unroll")                                                           \
      for (int r = 0; r < 4; ++r) {                                               \
        if (jb + g * 4 + r > QGS) S0[r] = -1e30f;                                 \
        if (jb + 16 + g * 4 + r > QGS) S1[r] = -1e30f;                            \
      }                                                                           \
    }                                                                             \
    _Pragma("unroll")                                                             \
    for (int r = 0; r < 4; ++r) {                                                 \
      S0[r] = exp2fast(S0[r]);                                                    \
      S1[r] = exp2fast(S1[r]);                                                    \
    }                                                                             \
    LS += ((S0[0] + S0[1]) + (S0[2] + S0[3])) + ((S1[0] + S1[1]) + (S1[2] + S1[3])); \
    u32 a0 = pack2(S0[0], S0[1]);                                                 \
    u32 a1 = pack2(S0[2], S0[3]);                                                 \
    u32 b0 = pack2(S1[0], S1[1]);                                                 \
    u32 b1 = pack2(S1[2], S1[3]);                                                 \
    asm("v_permlane32_swap_b32 %0, %1" : "+v"(a0), "+v"(b0));                     \
    asm("v_permlane16_swap_b32 %0, %1" : "+v"(a0), "+v"(b0));                     \
    asm("v_permlane32_swap_b32 %0, %1" : "+v"(a1), "+v"(b1));                     \
    asm("v_permlane16_swap_b32 %0, %1" : "+v"(a1), "+v"(b1));                     \
    PBS.u[0] = a0;                                                                \
    PBS.u[1] = a1;                                                                \
    PBS.u[2] = b0;                                                                \
    PBS.u[3] = b1;                                                                \
  }

  // STEP for iteration jt: S_cur = S(jt) ready; KN holds K(jt+1); KL gets K(jt+2);
  // AVC = V(jt) ready; AVN gets V(jt+1).
#define ATTN_STEP(SA0C, SA1C, SB0C, SB1C, SA0N, SA1N, SB0N, SB1N, KN0, KN1, KL0, KL1, AVC, AVN) \
  {                                                                               \
    const int jb = jt * 32;                                                       \
    const int jn1 = (jt + 1 < sB) ? jt + 1 : jt;                                  \
    const int jn2 = (jt + 2 < sB) ? jt + 2 : jt;                                  \
    /* 1: S(jt+1) from K-regs loaded last step */                                 \
    SB0N = (f32x4){0.f, 0.f, 0.f, 0.f}; SB1N = SB0N;                              \
    __builtin_amdgcn_s_setprio(1);                                                \
    _Pragma("unroll")                                                             \
    for (int ks = 0; ks < 3; ++ks) {                                              \
      SB0N = MFMA16(KN0[ks], aqB[ks], SB0N);                                      \
      SB1N = MFMA16(KN1[ks], aqB[ks], SB1N);                                      \
    }                                                                             \
    if (jt + 1 < sA) {                                                            \
      SA0N = (f32x4){0.f, 0.f, 0.f, 0.f}; SA1N = SA0N;                            \
      _Pragma("unroll")                                                           \
      for (int ks = 0; ks < 3; ++ks) {                                            \
        SA0N = MFMA16(KN0[ks], aqA[ks], SA0N);                                    \
        SA1N = MFMA16(KN1[ks], aqA[ks], SA1N);                                    \
      }                                                                           \
    }                                                                             \
    __builtin_amdgcn_s_setprio(0);                                                \
    /* 2: prefetch K(jt+2) from fragment-order Kf (contiguous 1KB per kc) */      \
    const u16* kp = Kfrag + (size_t)jn2 * 3072 + laneoff;                         \
    _Pragma("unroll")                                                             \
    for (int ks = 0; ks < 3; ++ks) {                                              \
      KL0[ks] = *(const bf16x8*)(kp + ks * 512);                                  \
      KL1[ks] = *(const bf16x8*)(kp + (3 + ks) * 512);                            \
    }                                                                             \
    /* 3: prefetch V(jt+1) */                                                     \
    _Pragma("unroll")                                                             \
    for (int n = 0; n < 4; ++n)                                                   \
      AVN[n] = *(const bf16x8*)(Vlane + (size_t)jn1 * 2048 + n * 512);            \
    /* 4: GLUE on ready S(jt) */                                                  \
    union { u32 u[4]; bf16x8 bv; } pbB, pbA;                                      \
    GLUE(SB0C, SB1C, q0B, qgB, lB, pbB);                                          \
    const bool actA = (jt < sA);                                                  \
    if (actA) GLUE(SA0C, SA1C, q0A, qgA, lA, pbA);                                \
    /* 5: PV on V loaded last step */                                             \
    __builtin_amdgcn_s_setprio(1);                                                \
    _Pragma("unroll")                                                             \
    for (int n = 0; n < 4; ++n) accB[n] = MFMA16(AVC[n], pbB.bv, accB[n]);        \
    if (actA) {                                                                   \
      _Pragma("unroll")                                                           \
      for (int n = 0; n < 4; ++n) accA[n] = MFMA16(AVC[n], pbA.bv, accA[n]);      \
    }                                                                             \
    __builtin_amdgcn_s_setprio(0);                                                \
  }

  int jt = 0;
  for (;;) {
    ATTN_STEP(SA0c, SA1c, SB0c, SB1c, SA0n, SA1n, SB0n, SB1n, kY0, kY1, kX0, kX1, avX, avY);
    if (++jt >= sB) break;
    ATTN_STEP(SA0n, SA1n, SB0n, SB1n, SA0c, SA1c, SB0c, SB1c, kX0, kX1, kY0, kY1, avY, avX);
    if (++jt >= sB) break;
  }
#undef ATTN_STEP
#undef GLUE

  // epilogue: reduce row-sum partials across the 4 g-groups, normalize, store (both streams)
  lA += __shfl_xor(lA, 16);
  lA += __shfl_xor(lA, 32);
  lB += __shfl_xor(lB, 16);
  lB += __shfl_xor(lB, 32);
  const float invA = 1.0f / lA;
  const float invB = 1.0f / lB;
  u32* dstA = (u32*)(AO + (size_t)qgA * 1024 + h * 64 + g * 4);
  u32* dstB = (u32*)(AO + (size_t)qgB * 1024 + h * 64 + g * 4);
#pragma unroll
  for (int n = 0; n < 4; ++n) {
    dstA[n * 8 + 0] = pack2(accA[n][0] * invA, accA[n][1] * invA);
    dstA[n * 8 + 1] = pack2(accA[n][2] * invA, accA[n][3] * invA);
    dstB[n * 8 + 0] = pack2(accB[n][0] * invB, accB[n][1] * invB);
    dstB[n * 8 + 1] = pack2(accB[n][2] * invB, accB[n][3] * invB);
  }
}

// ---------------- GEMM out: AO @ WoutT + bout  (M=2048, N=1024, K=1024), 128x32 tile ----------------
__global__ __launch_bounds__(256) void k_gemm_out(const u16* __restrict__ AO, const u16* __restrict__ WoT,
                                                  const float* __restrict__ bout, float* __restrict__ out) {
  __shared__ __align__(16) u16 ldsA[128 * 64];
  __shared__ __align__(16) u16 ldsB[32 * 64];
  const int bid = blockIdx.x;                     // 512 blocks = 2/CU
  const int bn = bid & 31, bm = bid >> 5;
  const int tid = threadIdx.x;
  const int wave = tid >> 6, lane = tid & 63;
  const int wr = wave >> 1, wc = wave & 1;
  const int g = lane >> 4, l15 = lane & 15;

  f32x4 acc[4];
#pragma unroll
  for (int m = 0; m < 4; ++m) acc[m] = (f32x4){0.f, 0.f, 0.f, 0.f};

  for (int k0 = 0; k0 < 1024; k0 += 64) {
#pragma unroll
    for (int li = 0; li < 4; ++li) {
      const int f = li * 256 + wave * 64 + lane;
      const int row = f >> 3;
      const int slot = f & 7;
      const int gcol = ((slot ^ (row & 7)) << 3);
      gload16(AO + (size_t)(bm * 128 + row) * 1024 + k0 + gcol, ldsA + (size_t)(li * 256 + wave * 64) * 8);
    }
    {
      const int f = wave * 64 + lane;            // 256 chunks = 32 rows x 64 cols
      const int row = f >> 3;
      const int slot = f & 7;
      const int gcol = ((slot ^ (row & 7)) << 3);
      gload16(WoT + (size_t)(bn * 32 + row) * 1024 + k0 + gcol, ldsB + (size_t)(wave * 64) * 8);
    }
    __syncthreads();
    bf16x8 af[4][2], bfr[2];
#pragma unroll
    for (int kk = 0; kk < 2; ++kk) {
#pragma unroll
      for (int m = 0; m < 4; ++m) {
        const int rowA = wr * 64 + m * 16 + l15;
        const int chA = (kk * 4 + g) ^ (rowA & 7);
        af[m][kk] = *(const bf16x8*)(ldsA + (size_t)rowA * 64 + chA * 8);
      }
      const int rowB = wc * 16 + l15;
      const int chB = (kk * 4 + g) ^ (rowB & 7);
      bfr[kk] = *(const bf16x8*)(ldsB + (size_t)rowB * 64 + chB * 8);
    }
#pragma unroll
    for (int m = 0; m < 4; ++m)
#pragma unroll
      for (int kk = 0; kk < 2; ++kk)
        acc[m] = MFMA16(af[m][kk], bfr[kk], acc[m]);
    __syncthreads();
  }

  const int tbase = bm * 128 + wr * 64 + g * 4;
  const int c = bn * 32 + wc * 16 + l15;
  const float bb = bout[c];
#pragma unroll
  for (int m = 0; m < 4; ++m)
#pragma unroll
    for (int r = 0; r < 4; ++r) {
      const int t = tbase + m * 16 + r;
      out[(size_t)t * 1024 + c] = acc[m][r] + bb;
    }
}

// ---------------- launch ----------------
extern "C" void kernel_launch(void* const* d_in, const int* in_sizes, int n_in,
                              void* d_out, int out_size, void* d_ws, size_t ws_size,
                              hipStream_t stream) {
  const float* x      = (const float*)d_in[0];
  const float* Wqkv   = (const float*)d_in[1];
  const float* bqkv   = (const float*)d_in[2];
  const float* W1p    = (const float*)d_in[3];
  const float* W2p    = (const float*)d_in[4];
  const float* pscale = (const float*)d_in[5];
  const float* Wout   = (const float*)d_in[6];
  const float* bout   = (const float*)d_in[7];
  float* out = (float*)d_out;

  char* ws = (char*)d_ws;
  u16*   WB    = (u16*)(ws + 0);          // [3200][1024] bf16
  u16*   WoT   = (u16*)(ws + 6553600);    // [1024][1024] bf16
  u16*   xb    = (u16*)(ws + 8650752);    // [2048][1024] bf16
  u16*   Qext  = (u16*)(ws + 12845056);   // [16][2048][96] bf16 (q*0.1803 | s*log2e*L | 0)
  u16*   Kf    = (u16*)(ws + 19136512);   // [16][64][6][64][8] bf16 (K in MFMA-fragment order)
  u16*   Vt    = (u16*)(ws + 25427968);   // [16][64][64][32] bf16 (tiled V^T)
  float* P12   = (float*)(ws + 29622272); // [2048][128] f32
  u16*   AO    = (u16*)(ws + 30670848);   // [2048][1024] bf16
  u32*   cnt   = (u32*)(ws + 34865152);   // persistent-GEMM work-steal counter

  hipMemsetAsync(cnt, 0, 4, stream);
  k_prep<<<3584, 256, 0, stream>>>(Wqkv, Wout, W1p, W2p, x, WB, WoT, xb);
  k_gemm_qkvp<<<768, 256, 0, stream>>>(xb, WB, bqkv, Qext, Kf, Vt, P12, cnt);
  k_lines<<<128, 256, 0, stream>>>(P12, pscale, Qext, Kf);
  k_attn<<<1024, 64, 0, stream>>>(Qext, Kf, Vt, AO);
  k_gemm_out<<<512, 256, 0, stream>>>(AO, WoT, bout, out);
}

// Round 17
// 91.808 us; speedup vs baseline: 1.1852x; 1.1852x over previous
//
#include <hip/hip_runtime.h>

typedef unsigned short u16;
typedef unsigned int u32;
typedef __attribute__((ext_vector_type(8))) __bf16 bf16x8;
typedef __attribute__((ext_vector_type(4))) float f32x4;
typedef __attribute__((ext_vector_type(4))) u16 u16x4;

#define MFMA16(a, b, c) __builtin_amdgcn_mfma_f32_16x16x32_bf16((a), (b), (c), 0, 0, 0)

static __device__ __forceinline__ u16 f2b(float f) {
  union { float f; u32 u; } v; v.f = f;
  u32 u = v.u;
  return (u16)((u + 0x7FFFu + ((u >> 16) & 1u)) >> 16);
}

// packed f32x2 -> bf16x2 (RNE), low half = a
static __device__ __forceinline__ u32 pack2(float a, float b) {
  u32 r;
  asm("v_cvt_pk_bf16_f32 %0, %1, %2" : "=v"(r) : "v"(a), "v"(b));
  return r;
}

static __device__ __forceinline__ float exp2fast(float x) {
#if defined(__has_builtin) && __has_builtin(__builtin_amdgcn_exp2f)
  return __builtin_amdgcn_exp2f(x);
#else
  return __expf(x * 0.6931471805599453f);
#endif
}

static __device__ __forceinline__ void gload16(const u16* gp, u16* lp) {
  __builtin_amdgcn_global_load_lds((__attribute__((address_space(1))) void*)(u16*)gp,
                                   (__attribute__((address_space(3))) void*)lp, 16, 0, 0);
}

// ---------------- merged prep kernel ----------------
__global__ __launch_bounds__(256) void k_prep(const float* __restrict__ Wqkv, const float* __restrict__ Wout,
                                              const float* __restrict__ W1p, const float* __restrict__ W2p,
                                              const float* __restrict__ x,
                                              u16* __restrict__ WB, u16* __restrict__ WoT,
                                              u16* __restrict__ xb) {
  const int b = blockIdx.x;
  const int t = threadIdx.x;
  if (b < 1024) {
    __shared__ float tile[64][65];
    const float* src; u16* dst; int N, n0, k0;
    if (b < 768) { src = Wqkv; dst = WB;  N = 3072; n0 = (b % 48) * 64; k0 = (b / 48) * 64; }
    else { const int bb = b - 768; src = Wout; dst = WoT; N = 1024; n0 = (bb & 15) * 64; k0 = (bb >> 4) * 64; }
    const int rr = t >> 4, cc = (t & 15) << 2;
#pragma unroll
    for (int i = 0; i < 4; ++i) {
      const float4 v = *(const float4*)(src + (size_t)(k0 + rr + i * 16) * N + n0 + cc);
      tile[rr + i * 16][cc + 0] = v.x; tile[rr + i * 16][cc + 1] = v.y;
      tile[rr + i * 16][cc + 2] = v.z; tile[rr + i * 16][cc + 3] = v.w;
    }
    __syncthreads();
    const int nr = t >> 3, kc = (t & 7) << 3;
#pragma unroll
    for (int i = 0; i < 2; ++i) {
      u16 o[8];
#pragma unroll
      for (int j = 0; j < 8; ++j) o[j] = f2b(tile[kc + j][nr + i * 32]);
      *(uint4*)(dst + (size_t)(n0 + nr + i * 32) * 1024 + k0 + kc) = *(const uint4*)o;
    }
  } else if (b < 1536) {
    const int idx = (b - 1024) * 256 + t;  // 131072
    const int j = idx >> 10, k = idx & 1023;
    const float v = (j < 64) ? W1p[(size_t)k * 64 + j] : W2p[(size_t)k * 64 + (j - 64)];
    WB[(size_t)3072 * 1024 + idx] = f2b(v);
  } else {
    const size_t idx = ((size_t)(b - 1536) * 256 + t) << 2;
    const float4 v = *(const float4*)(x + idx);
    u16x4 o; o.x = f2b(v.x); o.y = f2b(v.y); o.z = f2b(v.z); o.w = f2b(v.w);
    *(u16x4*)(xb + idx) = o;
  }
}

// ---------------- 128x64 bf16 MFMA GEMM core (BK=64, global_load_lds, XOR swizzle) ----------------
static __device__ __forceinline__ void gemm_core_128x64(const u16* __restrict__ A, const u16* __restrict__ B,
                                                        int brow, int bcol, int K,
                                                        u16* ldsA, u16* ldsB, f32x4 acc[4][2]) {
  const int tid = threadIdx.x;
  const int wave = tid >> 6, lane = tid & 63;
  const int wr = wave >> 1, wc = wave & 1;
  const int g = lane >> 4, l15 = lane & 15;

  for (int k0 = 0; k0 < K; k0 += 64) {
#pragma unroll
    for (int li = 0; li < 4; ++li) {
      const int f = li * 256 + wave * 64 + lane;
      const int row = f >> 3;
      const int slot = f & 7;
      const int gcol = ((slot ^ (row & 7)) << 3);
      gload16(A + (size_t)(brow + row) * K + k0 + gcol, ldsA + (size_t)(li * 256 + wave * 64) * 8);
    }
#pragma unroll
    for (int li = 0; li < 2; ++li) {
      const int f = li * 256 + wave * 64 + lane;
      const int row = f >> 3;
      const int slot = f & 7;
      const int gcol = ((slot ^ (row & 7)) << 3);
      gload16(B + (size_t)(bcol + row) * K + k0 + gcol, ldsB + (size_t)(li * 256 + wave * 64) * 8);
    }
    __syncthreads();
    bf16x8 af[4][2], bfr[2][2];
#pragma unroll
    for (int kk = 0; kk < 2; ++kk) {
#pragma unroll
      for (int m = 0; m < 4; ++m) {
        const int rowA = wr * 64 + m * 16 + l15;
        const int chA = (kk * 4 + g) ^ (rowA & 7);
        af[m][kk] = *(const bf16x8*)(ldsA + (size_t)rowA * 64 + chA * 8);
      }
#pragma unroll
      for (int n = 0; n < 2; ++n) {
        const int rowB = wc * 32 + n * 16 + l15;
        const int chB = (kk * 4 + g) ^ (rowB & 7);
        bfr[n][kk] = *(const bf16x8*)(ldsB + (size_t)rowB * 64 + chB * 8);
      }
    }
#pragma unroll
    for (int m = 0; m < 4; ++m)
#pragma unroll
      for (int n = 0; n < 2; ++n)
#pragma unroll
        for (int kk = 0; kk < 2; ++kk)
          acc[m][n] = MFMA16(af[m][kk], bfr[n][kk], acc[m][n]);
    __syncthreads();
  }
}

// ---------------- GEMM1: x @ [Wqkv|W1p|W2p]  (M=2048, N=3200, K=1024), 128x64 tile ----------------
// K written in MFMA-FRAGMENT ORDER: Kf[h][jt][half*3+ks][lane=g*16+l15][e] (6KB/32-row tile).
// V stored TILED: Vt[h][jt][d][tin] = [h][64][64][32].
__global__ __launch_bounds__(256) void k_gemm_qkvp(const u16* __restrict__ xb, const u16* __restrict__ WB,
                                                   const float* __restrict__ bqkv,
                                                   u16* __restrict__ Qext, u16* __restrict__ Kf,
                                                   u16* __restrict__ Vt, float* __restrict__ P12) {
  __shared__ __align__(16) u16 ldsA[128 * 64];
  __shared__ __align__(16) u16 ldsB[64 * 64];
  const int bid = blockIdx.x;                      // 800 blocks
  const int bn = bid % 50, bm = bid / 50;
  f32x4 acc[4][2];
#pragma unroll
  for (int m = 0; m < 4; ++m)
#pragma unroll
    for (int n = 0; n < 2; ++n) acc[m][n] = (f32x4){0.f, 0.f, 0.f, 0.f};
  gemm_core_128x64(xb, WB, bm * 128, bn * 64, 1024, ldsA, ldsB, acc);

  const int tid = threadIdx.x;
  const int wave = tid >> 6, lane = tid & 63;
  const int wr = wave >> 1, wc = wave & 1;
  const int g = lane >> 4, l15 = lane & 15;
  const int tbase = bm * 128 + wr * 64 + g * 4;
  const int cbase = bn * 64 + wc * 32 + l15;
#pragma unroll
  for (int m = 0; m < 4; ++m) {
#pragma unroll
    for (int n = 0; n < 2; ++n) {
      const int c = cbase + n * 16;
#pragma unroll
      for (int r = 0; r < 4; ++r) {
        const int t = tbase + m * 16 + r;
        float v = acc[m][n][r];
        if (c < 3072) {
          v += bqkv[c];
          const int sub = c >> 10;
          const int rem = c & 1023;
          const int hh = rem >> 6, d = rem & 63;
          if (sub == 0) {
            Qext[((size_t)hh * 2048 + t) * 96 + d] = f2b(v * 0.18033688f);
          } else if (sub == 1) {
            const int jt2 = t >> 5, hf = (t >> 4) & 1, l15t = t & 15;
            const int ks2 = d >> 5, gg = (d >> 3) & 3, e = d & 7;
            Kf[(size_t)hh * 196608 + (size_t)jt2 * 3072 + (hf * 3 + ks2) * 512 + (gg * 16 + l15t) * 8 + e] = f2b(v);
          } else {
            Vt[(size_t)hh * 131072 + (size_t)(t >> 5) * 2048 + d * 32 + (t & 31)] = f2b(v);
          }
        } else {
          P12[(size_t)t * 128 + (c - 3072)] = v;
        }
      }
    }
  }
}

// ---------------- Plucker lines -> Qext cols 64..95 + Kf fragment block ks=2 ----------------
__global__ __launch_bounds__(256) void k_lines(const float* __restrict__ P12, const float* __restrict__ pscale,
                                               u16* __restrict__ Qext, u16* __restrict__ Kf) {
  const int idx = blockIdx.x * 256 + threadIdx.x;  // 32768 = 2048*16
  const int t = idx >> 4, h = idx & 15;
  const float* p = P12 + (size_t)t * 128;
  const float a0 = p[h * 4 + 0], a1 = p[h * 4 + 1], a2 = p[h * 4 + 2], a3 = p[h * 4 + 3];
  const float b0 = p[64 + h * 4 + 0], b1 = p[64 + h * 4 + 1], b2 = p[64 + h * 4 + 2], b3 = p[64 + h * 4 + 3];
  float L0 = a0 * b1 - a1 * b0;
  float L1 = a0 * b2 - a2 * b0;
  float L2 = a0 * b3 - a3 * b0;
  float L3 = a1 * b2 - a2 * b1;
  float L4 = a1 * b3 - a3 * b1;
  float L5 = a2 * b3 - a3 * b2;
  const float nrm = sqrtf(L0 * L0 + L1 * L1 + L2 * L2 + L3 * L3 + L4 * L4 + L5 * L5);
  const float inv = 1.0f / fmaxf(nrm, 1e-12f);
  L0 *= inv; L1 *= inv; L2 *= inv; L3 *= inv; L4 *= inv; L5 *= inv;
  const float s = pscale[h] * 1.44269504f;  // fold log2(e) into q-side bias
  u16* q = Qext + ((size_t)h * 2048 + t) * 96 + 64;
  q[0] = f2b(L0 * s); q[1] = f2b(L1 * s); q[2] = f2b(L2 * s);
  q[3] = f2b(L3 * s); q[4] = f2b(L4 * s); q[5] = f2b(L5 * s);
#pragma unroll
  for (int c = 6; c < 32; ++c) q[c] = 0;
  // Jlines = J6 @ L : [L5, -L4, L3, L2, -L1, L0] -> fragment-order block z = half*3+2
  const float kv0 = L5, kv1 = -L4, kv2 = L3, kv3 = L2, kv4 = -L1, kv5 = L0;
  const int jt = t >> 5, hf = (t >> 4) & 1, l15t = t & 15;
  u16* kf = Kf + (size_t)h * 196608 + (size_t)jt * 3072 + (hf * 3 + 2) * 512;
#pragma unroll
  for (int j = 0; j < 32; ++j) {
    const int gg = (j >> 3) & 3, e = j & 7;
    float val;
    if (j == 0) val = kv0; else if (j == 1) val = kv1; else if (j == 2) val = kv2;
    else if (j == 3) val = kv3; else if (j == 4) val = kv4; else if (j == 5) val = kv5;
    else val = 0.f;
    kf[(gg * 16 + l15t) * 8 + e] = (j < 6) ? f2b(val) : (u16)0;
  }
}

// ---------------- fused causal attention: paired dual-stream + pipelined, fragment-order K ----------------
__global__ __launch_bounds__(64) void k_attn(const u16* __restrict__ Qext, const u16* __restrict__ Kf,
                                             const u16* __restrict__ Vt, u16* __restrict__ AO) {
  const int bid = blockIdx.x;                     // 1024 blocks = 16 heads x 64 pairs
  const int h = bid & 15;
  const int p = bid >> 4;                         // 0..63
  const int lane = threadIdx.x;
  const int g = lane >> 4, l15 = lane & 15;
  const int q0A = p << 4;
  const int q0B = (127 - p) << 4;
  const int qgA = q0A + l15;
  const int qgB = q0B + l15;
  const int sA = (p >> 1) + 1;                    // steps for tile A
  const int sB = ((127 - p) >> 1) + 1;            // steps for tile B (> sA)
  const u16* Qh = Qext + (size_t)h * 2048 * 96;
  const u16* Kfrag = Kf + (size_t)h * 196608;     // + jt*3072 + z*512 + lane*8
  const u16* Vh = Vt + (size_t)h * 131072;

  bf16x8 aqA[3], aqB[3];
#pragma unroll
  for (int ks = 0; ks < 3; ++ks) {
    aqA[ks] = *(const bf16x8*)(Qh + (size_t)qgA * 96 + ks * 32 + g * 8);
    aqB[ks] = *(const bf16x8*)(Qh + (size_t)qgB * 96 + ks * 32 + g * 8);
  }

  f32x4 accA[4], accB[4];
#pragma unroll
  for (int n = 0; n < 4; ++n) {
    accA[n] = (f32x4){0.f, 0.f, 0.f, 0.f};
    accB[n] = (f32x4){0.f, 0.f, 0.f, 0.f};
  }
  float lA = 0.f, lB = 0.f;

  const u16* Vlane = Vh + (size_t)l15 * 32 + g * 8;   // + jt*2048 + n*512
  const int laneoff = lane * 8;

  bf16x8 kX0[3], kX1[3], kY0[3], kY1[3];
  bf16x8 avX[4], avY[4];
  f32x4 SA0c, SA1c, SB0c, SB1c, SA0n, SA1n, SB0n, SB1n;

  // ---- prologue: K(0)->kX, S(0), K(1)->kY, V(0)->avX
  {
    const u16* kp0 = Kfrag + laneoff;
#pragma unroll
    for (int ks = 0; ks < 3; ++ks) {
      kX0[ks] = *(const bf16x8*)(kp0 + ks * 512);
      kX1[ks] = *(const bf16x8*)(kp0 + (3 + ks) * 512);
    }
    SB0c = (f32x4){0.f, 0.f, 0.f, 0.f}; SB1c = SB0c; SA0c = SB0c; SA1c = SB0c;
#pragma unroll
    for (int ks = 0; ks < 3; ++ks) {
      SB0c = MFMA16(kX0[ks], aqB[ks], SB0c);
      SB1c = MFMA16(kX1[ks], aqB[ks], SB1c);
      SA0c = MFMA16(kX0[ks], aqA[ks], SA0c);
      SA1c = MFMA16(kX1[ks], aqA[ks], SA1c);
    }
    const u16* kp = Kfrag + (size_t)((1 < sB) ? 1 : 0) * 3072 + laneoff;
#pragma unroll
    for (int ks = 0; ks < 3; ++ks) {
      kY0[ks] = *(const bf16x8*)(kp + ks * 512);
      kY1[ks] = *(const bf16x8*)(kp + (3 + ks) * 512);
    }
#pragma unroll
    for (int n = 0; n < 4; ++n) avX[n] = *(const bf16x8*)(Vlane + n * 512);
  }

#define GLUE(S0, S1, Q0S, QGS, LS, PBS)                                           \
  {                                                                               \
    if (jb + 31 > Q0S) {                                                          \
      _Pragma("unroll")                                                           \
      for (int r = 0; r < 4; ++r) {                                               \
        if (jb + g * 4 + r > QGS) S0[r] = -1e30f;                                 \
        if (jb + 16 + g * 4 + r > QGS) S1[r] = -1e30f;                            \
      }                                                                           \
    }                                                                             \
    _Pragma("unroll")                                                             \
    for (int r = 0; r < 4; ++r) {                                                 \
      S0[r] = exp2fast(S0[r]);                                                    \
      S1[r] = exp2fast(S1[r]);                                                    \
    }                                                                             \
    LS += ((S0[0] + S0[1]) + (S0[2] + S0[3])) + ((S1[0] + S1[1]) + (S1[2] + S1[3])); \
    u32 a0 = pack2(S0[0], S0[1]);                                                 \
    u32 a1 = pack2(S0[2], S0[3]);                                                 \
    u32 b0 = pack2(S1[0], S1[1]);                                                 \
    u32 b1 = pack2(S1[2], S1[3]);                                                 \
    asm("v_permlane32_swap_b32 %0, %1" : "+v"(a0), "+v"(b0));                     \
    asm("v_permlane16_swap_b32 %0, %1" : "+v"(a0), "+v"(b0));                     \
    asm("v_permlane32_swap_b32 %0, %1" : "+v"(a1), "+v"(b1));                     \
    asm("v_permlane16_swap_b32 %0, %1" : "+v"(a1), "+v"(b1));                     \
    PBS.u[0] = a0;                                                                \
    PBS.u[1] = a1;                                                                \
    PBS.u[2] = b0;                                                                \
    PBS.u[3] = b1;                                                                \
  }

  // STEP for iteration jt: S_cur = S(jt) ready; KN holds K(jt+1); KL gets K(jt+2);
  // AVC = V(jt) ready; AVN gets V(jt+1).
#define ATTN_STEP(SA0C, SA1C, SB0C, SB1C, SA0N, SA1N, SB0N, SB1N, KN0, KN1, KL0, KL1, AVC, AVN) \
  {                                                                               \
    const int jb = jt * 32;                                                       \
    const int jn1 = (jt + 1 < sB) ? jt + 1 : jt;                                  \
    const int jn2 = (jt + 2 < sB) ? jt + 2 : jt;                                  \
    /* 1: S(jt+1) from K-regs loaded last step */                                 \
    SB0N = (f32x4){0.f, 0.f, 0.f, 0.f}; SB1N = SB0N;                              \
    __builtin_amdgcn_s_setprio(1);                                                \
    _Pragma("unroll")                                                             \
    for (int ks = 0; ks < 3; ++ks) {                                              \
      SB0N = MFMA16(KN0[ks], aqB[ks], SB0N);                                      \
      SB1N = MFMA16(KN1[ks], aqB[ks], SB1N);                                      \
    }                                                                             \
    if (jt + 1 < sA) {                                                            \
      SA0N = (f32x4){0.f, 0.f, 0.f, 0.f}; SA1N = SA0N;                            \
      _Pragma("unroll")                                                           \
      for (int ks = 0; ks < 3; ++ks) {                                            \
        SA0N = MFMA16(KN0[ks], aqA[ks], SA0N);                                    \
        SA1N = MFMA16(KN1[ks], aqA[ks], SA1N);                                    \
      }                                                                           \
    }                                                                             \
    __builtin_amdgcn_s_setprio(0);                                                \
    /* 2: prefetch K(jt+2) from fragment-order Kf (contiguous 1KB per kc) */      \
    const u16* kp = Kfrag + (size_t)jn2 * 3072 + laneoff;                         \
    _Pragma("unroll")                                                             \
    for (int ks = 0; ks < 3; ++ks) {                                              \
      KL0[ks] = *(const bf16x8*)(kp + ks * 512);                                  \
      KL1[ks] = *(const bf16x8*)(kp + (3 + ks) * 512);                            \
    }                                                                             \
    /* 3: prefetch V(jt+1) */                                                     \
    _Pragma("unroll")                                                             \
    for (int n = 0; n < 4; ++n)                                                   \
      AVN[n] = *(const bf16x8*)(Vlane + (size_t)jn1 * 2048 + n * 512);            \
    /* 4: GLUE on ready S(jt) */                                                  \
    union { u32 u[4]; bf16x8 bv; } pbB, pbA;                                      \
    GLUE(SB0C, SB1C, q0B, qgB, lB, pbB);                                          \
    const bool actA = (jt < sA);                                                  \
    if (actA) GLUE(SA0C, SA1C, q0A, qgA, lA, pbA);                                \
    /* 5: PV on V loaded last step */                                             \
    __builtin_amdgcn_s_setprio(1);                                                \
    _Pragma("unroll")                                                             \
    for (int n = 0; n < 4; ++n) accB[n] = MFMA16(AVC[n], pbB.bv, accB[n]);        \
    if (actA) {                                                                   \
      _Pragma("unroll")                                                           \
      for (int n = 0; n < 4; ++n) accA[n] = MFMA16(AVC[n], pbA.bv, accA[n]);      \
    }                                                                             \
    __builtin_amdgcn_s_setprio(0);                                                \
  }

  int jt = 0;
  for (;;) {
    ATTN_STEP(SA0c, SA1c, SB0c, SB1c, SA0n, SA1n, SB0n, SB1n, kY0, kY1, kX0, kX1, avX, avY);
    if (++jt >= sB) break;
    ATTN_STEP(SA0n, SA1n, SB0n, SB1n, SA0c, SA1c, SB0c, SB1c, kX0, kX1, kY0, kY1, avY, avX);
    if (++jt >= sB) break;
  }
#undef ATTN_STEP
#undef GLUE

  // epilogue: reduce row-sum partials across the 4 g-groups, normalize, store (both streams)
  lA += __shfl_xor(lA, 16);
  lA += __shfl_xor(lA, 32);
  lB += __shfl_xor(lB, 16);
  lB += __shfl_xor(lB, 32);
  const float invA = 1.0f / lA;
  const float invB = 1.0f / lB;
  u32* dstA = (u32*)(AO + (size_t)qgA * 1024 + h * 64 + g * 4);
  u32* dstB = (u32*)(AO + (size_t)qgB * 1024 + h * 64 + g * 4);
#pragma unroll
  for (int n = 0; n < 4; ++n) {
    dstA[n * 8 + 0] = pack2(accA[n][0] * invA, accA[n][1] * invA);
    dstA[n * 8 + 1] = pack2(accA[n][2] * invA, accA[n][3] * invA);
    dstB[n * 8 + 0] = pack2(accB[n][0] * invB, accB[n][1] * invB);
    dstB[n * 8 + 1] = pack2(accB[n][2] * invB, accB[n][3] * invB);
  }
}

// ---------------- GEMM out: AO @ WoutT + bout  (M=2048, N=1024, K=1024), 128x32 tile ----------------
__global__ __launch_bounds__(256) void k_gemm_out(const u16* __restrict__ AO, const u16* __restrict__ WoT,
                                                  const float* __restrict__ bout, float* __restrict__ out) {
  __shared__ __align__(16) u16 ldsA[128 * 64];
  __shared__ __align__(16) u16 ldsB[32 * 64];
  const int bid = blockIdx.x;                     // 512 blocks = 2/CU
  const int bn = bid & 31, bm = bid >> 5;
  const int tid = threadIdx.x;
  const int wave = tid >> 6, lane = tid & 63;
  const int wr = wave >> 1, wc = wave & 1;
  const int g = lane >> 4, l15 = lane & 15;

  f32x4 acc[4];
#pragma unroll
  for (int m = 0; m < 4; ++m) acc[m] = (f32x4){0.f, 0.f, 0.f, 0.f};

  for (int k0 = 0; k0 < 1024; k0 += 64) {
#pragma unroll
    for (int li = 0; li < 4; ++li) {
      const int f = li * 256 + wave * 64 + lane;
      const int row = f >> 3;
      const int slot = f & 7;
      const int gcol = ((slot ^ (row & 7)) << 3);
      gload16(AO + (size_t)(bm * 128 + row) * 1024 + k0 + gcol, ldsA + (size_t)(li * 256 + wave * 64) * 8);
    }
    {
      const int f = wave * 64 + lane;            // 256 chunks = 32 rows x 64 cols
      const int row = f >> 3;
      const int slot = f & 7;
      const int gcol = ((slot ^ (row & 7)) << 3);
      gload16(WoT + (size_t)(bn * 32 + row) * 1024 + k0 + gcol, ldsB + (size_t)(wave * 64) * 8);
    }
    __syncthreads();
    bf16x8 af[4][2], bfr[2];
#pragma unroll
    for (int kk = 0; kk < 2; ++kk) {
#pragma unroll
      for (int m = 0; m < 4; ++m) {
        const int rowA = wr * 64 + m * 16 + l15;
        const int chA = (kk * 4 + g) ^ (rowA & 7);
        af[m][kk] = *(const bf16x8*)(ldsA + (size_t)rowA * 64 + chA * 8);
      }
      const int rowB = wc * 16 + l15;
      const int chB = (kk * 4 + g) ^ (rowB & 7);
      bfr[kk] = *(const bf16x8*)(ldsB + (size_t)rowB * 64 + chB * 8);
    }
#pragma unroll
    for (int m = 0; m < 4; ++m)
#pragma unroll
      for (int kk = 0; kk < 2; ++kk)
        acc[m] = MFMA16(af[m][kk], bfr[kk], acc[m]);
    __syncthreads();
  }

  const int tbase = bm * 128 + wr * 64 + g * 4;
  const int c = bn * 32 + wc * 16 + l15;
  const float bb = bout[c];
#pragma unroll
  for (int m = 0; m < 4; ++m)
#pragma unroll
    for (int r = 0; r < 4; ++r) {
      const int t = tbase + m * 16 + r;
      out[(size_t)t * 1024 + c] = acc[m][r] + bb;
    }
}

// ---------------- launch ----------------
extern "C" void kernel_launch(void* const* d_in, const int* in_sizes, int n_in,
                              void* d_out, int out_size, void* d_ws, size_t ws_size,
                              hipStream_t stream) {
  const float* x      = (const float*)d_in[0];
  const float* Wqkv   = (const float*)d_in[1];
  const float* bqkv   = (const float*)d_in[2];
  const float* W1p    = (const float*)d_in[3];
  const float* W2p    = (const float*)d_in[4];
  const float* pscale = (const float*)d_in[5];
  const float* Wout   = (const float*)d_in[6];
  const float* bout   = (const float*)d_in[7];
  float* out = (float*)d_out;

  char* ws = (char*)d_ws;
  u16*   WB    = (u16*)(ws + 0);          // [3200][1024] bf16
  u16*   WoT   = (u16*)(ws + 6553600);    // [1024][1024] bf16
  u16*   xb    = (u16*)(ws + 8650752);    // [2048][1024] bf16
  u16*   Qext  = (u16*)(ws + 12845056);   // [16][2048][96] bf16 (q*0.1803 | s*log2e*L | 0)
  u16*   Kf    = (u16*)(ws + 19136512);   // [16][64][6][64][8] bf16 (K in MFMA-fragment order)
  u16*   Vt    = (u16*)(ws + 25427968);   // [16][64][64][32] bf16 (tiled V^T)
  float* P12   = (float*)(ws + 29622272); // [2048][128] f32
  u16*   AO    = (u16*)(ws + 30670848);   // [2048][1024] bf16

  k_prep<<<3584, 256, 0, stream>>>(Wqkv, Wout, W1p, W2p, x, WB, WoT, xb);
  k_gemm_qkvp<<<800, 256, 0, stream>>>(xb, WB, bqkv, Qext, Kf, Vt, P12);
  k_lines<<<128, 256, 0, stream>>>(P12, pscale, Qext, Kf);
  k_attn<<<1024, 64, 0, stream>>>(Qext, Kf, Vt, AO);
  k_gemm_out<<<512, 256, 0, stream>>>(AO, WoT, bout, out);
}